// Round 8
// baseline (281.795 us; speedup 1.0000x reference)
//
#include <hip/hip_runtime.h>
#include <stdint.h>

typedef unsigned short u16;
typedef __attribute__((ext_vector_type(8))) short short8;
typedef __attribute__((ext_vector_type(4))) float f32x4;

#define M_DIM 8192
#define N_DIM 4096
#define K_DIM 4096

// ---------- fp32 -> bf16 (RNE), 8 elems/thread ----------
__device__ inline u16 f32_to_bf16_rne(float f) {
    uint32_t b = __builtin_bit_cast(uint32_t, f);
    b += 0x7fffu + ((b >> 16) & 1u);
    return (u16)(b >> 16);
}

__global__ __launch_bounds__(256)
void cvt_f32_to_bf16_k(const float* __restrict__ in, u16* __restrict__ out, int n_vec8) {
    int stride = gridDim.x * blockDim.x;
    for (int i = blockIdx.x * blockDim.x + threadIdx.x; i < n_vec8; i += stride) {
        const float4* p = reinterpret_cast<const float4*>(in) + 2 * (size_t)i;
        float4 a = p[0];
        float4 b = p[1];
        float v[8] = {a.x, a.y, a.z, a.w, b.x, b.y, b.z, b.w};
        short8 r;
#pragma unroll
        for (int j = 0; j < 8; ++j) r[j] = (short)f32_to_bf16_rne(v[j]);
        *reinterpret_cast<short8*>(out + 8 * (size_t)i) = r;
    }
}

// ---------- 256x256 8-phase bf16 GEMM (even-read schedule) ----------
// A: [M][K] bf16, B: [N][K] bf16 (B^T), C: [M][N] f32
// 512 threads = 8 waves (2M x 4N); per-wave 128x64; BK=64.
// LDS: [dbuf][mat][half][128*64] bf16 = 128 KiB. Swizzle S(a)=a^(((a>>7)&7)<<4),
// folded into precomputed per-lane base pointers.
//
// Quadrant order per tile: Q00(a0,b0) Q10(a1,b0) Q01(a0,b1) Q11(a1,b1).
// Per-iter wiring (reads max 8/wave/phase; JIT one phase ahead):
//   P1 Q00a | rd a1        (buf0.A.MH1)
//   P2 Q10a | rd b1        (buf0.B.NH1)          | vmcnt(0): publish tile b
//   P3 Q01a | st (a+2).A   | rd b0' (buf1.B.NH0)
//   P4 Q11a | st (a+2).B   | rd a0' (buf1.A.MH0)
//   P5 Q00b | rd a1'       (buf1.A.MH1)
//   P6 Q10b | rd b1'       (buf1.B.NH1)          | vmcnt(0): publish tile a+2
//   P7 Q01b | st (b+2).A   | rd b0''(buf0.B.NH0)
//   P8 Q11b | st (b+2).B   | rd a0''(buf0.A.MH0)
// WAR: each stage issues one close-barrier after its buffer's last read is
// lgkm-drained (read drains at P-open lgkm0, published at P-close BAR, stage
// issues after that BAR). Reg liveness: every overwrite >=1 phase after last
// use (a0 dead P3->P4, a1 P4->P5, b0 P2->P3, b1 P4->P6, etc.).
// vmcnt(0) at P2/P6: outstanding = exactly the 8 loads of the next tile,
// issued 2-3 phases earlier (~2.5k cyc >> 900 cy HBM) -> no stall.

#define BAR() do { asm volatile("" ::: "memory"); __builtin_amdgcn_s_barrier(); asm volatile("" ::: "memory"); } while (0)
#define WAIT_LGKM0() do { asm volatile("s_waitcnt lgkmcnt(0)" ::: "memory"); __builtin_amdgcn_sched_barrier(0); } while (0)
#define WAIT_VM8() asm volatile("s_waitcnt vmcnt(8)" ::: "memory")
#define WAIT_VM0() asm volatile("s_waitcnt vmcnt(0)" ::: "memory")
#define SB0() __builtin_amdgcn_sched_barrier(0)

// 16 MFMA: 4 m-frags x 2 n-frags x 2 k-slices
#define QUAD(AA, BB, MH, NH)                                                      \
    _Pragma("unroll")                                                             \
    for (int ks = 0; ks < 2; ++ks) {                                              \
        _Pragma("unroll")                                                         \
        for (int m = 0; m < 4; ++m) {                                             \
            _Pragma("unroll")                                                     \
            for (int n = 0; n < 2; ++n) {                                         \
                acc[(MH) * 4 + m][(NH) * 2 + n] =                                 \
                    __builtin_amdgcn_mfma_f32_16x16x32_bf16(                      \
                        AA[ks][m], BB[ks][n], acc[(MH) * 4 + m][(NH) * 2 + n],    \
                        0, 0, 0);                                                 \
            }                                                                     \
        }                                                                         \
    }

// A fragment reads: base pointers P0(ks=0)/P1(ks=1), MHOFF in {0, 8192} bytes
#define READ_A(P0, P1, AA, MHOFF)                                                 \
    _Pragma("unroll")                                                             \
    for (int m = 0; m < 4; ++m) {                                                 \
        AA[0][m] = *reinterpret_cast<const short8*>((P0) + (MHOFF) + m * 2048);   \
        AA[1][m] = *reinterpret_cast<const short8*>((P1) + (MHOFF) + m * 2048);   \
    }

// B fragment reads: NHOFF in {0, 4096} bytes
#define READ_B(P0, P1, BB, NHOFF)                                                 \
    _Pragma("unroll")                                                             \
    for (int n = 0; n < 2; ++n) {                                                 \
        BB[0][n] = *reinterpret_cast<const short8*>((P0) + (NHOFF) + n * 2048);   \
        BB[1][n] = *reinterpret_cast<const short8*>((P1) + (NHOFF) + n * 2048);   \
    }

__global__ __launch_bounds__(512, 2)
void gemm_8phase(const u16* __restrict__ A, const u16* __restrict__ B,
                 const float* __restrict__ bias, float* __restrict__ C) {
    __shared__ __align__(16) u16 lds[2][2][2][128 * 64];   // 128 KiB

    const int tid  = threadIdx.x;
    const int wave = tid >> 6;
    const int lane = tid & 63;

    // T1: XCD-aware bijective swizzle (nwg=512, 512%8==0)
    const uint32_t wg = (blockIdx.x & 7u) * 64u + (blockIdx.x >> 3);
    const int bx = (int)(wg % (N_DIM / 256));
    const int by = (int)(wg / (N_DIM / 256));
    const int brow = by * 256;
    const int bcol = bx * 256;

    const int wr = wave >> 2;   // 0..1 -> 128 output rows each
    const int wc = wave & 3;    // 0..3 -> 64 output cols each

    // staging: physical chunk cp (linear gload_lds dest) holds LOGICAL chunk
    // cl = cp ^ ((cp>>3)&7)  (16B-chunk form of S; involution)
    const uint32_t cp0 = (uint32_t)(wave * 64 + lane);
    const uint32_t cp1 = cp0 + 512u;
    const uint32_t cl0 = cp0 ^ ((cp0 >> 3) & 7u);
    const uint32_t cl1 = cp1 ^ ((cp1 >> 3) & 7u);
    const uint32_t sr0 = cl0 >> 3, sc0 = (cl0 & 7u) * 8u;
    const uint32_t sr1 = cl1 >> 3, sc1 = (cl1 & 7u) * 8u;

    const u16* pA[2] = { A + (size_t)(brow)       * K_DIM,
                         A + (size_t)(brow + 128) * K_DIM };
    const u16* pB[2] = { B + (size_t)(bcol)       * K_DIM,
                         B + (size_t)(bcol + 128) * K_DIM };

    // precomputed swizzled per-lane ds_read bases
    const uint32_t kb   = (uint32_t)(lane >> 4) * 16u;
    const uint32_t sw   = (uint32_t)(lane & 7) << 4;
    const uint32_t aoff = (uint32_t)(lane & 15) * 128u + kb;
    const uint32_t boff = (uint32_t)(wc & 1) * 8192u + (uint32_t)(lane & 15) * 128u + kb;

    const char* As0 = (const char*)&lds[0][0][wr][0];
    const char* As1 = (const char*)&lds[1][0][wr][0];
    const char* Bs0 = (const char*)&lds[0][1][wc >> 1][0];
    const char* Bs1 = (const char*)&lds[1][1][wc >> 1][0];

    const char* pA0k0 = As0 + ((aoff)        ^ sw);
    const char* pA0k1 = As0 + ((aoff + 64u)  ^ sw);
    const char* pA1k0 = As1 + ((aoff)        ^ sw);
    const char* pA1k1 = As1 + ((aoff + 64u)  ^ sw);
    const char* pB0k0 = Bs0 + ((boff)        ^ sw);
    const char* pB0k1 = Bs0 + ((boff + 64u)  ^ sw);
    const char* pB1k0 = Bs1 + ((boff)        ^ sw);
    const char* pB1k1 = Bs1 + ((boff + 64u)  ^ sw);

    auto STAGE = [&](const u16* gbase, u16* lhalf, int k0) {
        __builtin_amdgcn_global_load_lds(
            (const __attribute__((address_space(1))) uint32_t*)(gbase + (size_t)sr0 * K_DIM + k0 + sc0),
            (__attribute__((address_space(3))) uint32_t*)(lhalf + wave * 512), 16, 0, 0);
        __builtin_amdgcn_global_load_lds(
            (const __attribute__((address_space(1))) uint32_t*)(gbase + (size_t)sr1 * K_DIM + k0 + sc1),
            (__attribute__((address_space(3))) uint32_t*)(lhalf + 4096 + wave * 512), 16, 0, 0);
    };

    f32x4 acc[8][4];
#pragma unroll
    for (int m = 0; m < 8; ++m)
#pragma unroll
        for (int n = 0; n < 4; ++n) acc[m][n] = (f32x4){0.f, 0.f, 0.f, 0.f};

    short8 a0[2][4], a1[2][4], b0[2][2], b1[2][2];

    // ---- prologue: tiles 0 (buf0) and 1 (buf1); vmcnt(8); pre-read b0,a0 ----
    STAGE(pA[0], &lds[0][0][0][0], 0);
    STAGE(pA[1], &lds[0][0][1][0], 0);
    STAGE(pB[0], &lds[0][1][0][0], 0);
    STAGE(pB[1], &lds[0][1][1][0], 0);
    STAGE(pA[0], &lds[1][0][0][0], 64);
    STAGE(pA[1], &lds[1][0][1][0], 64);
    STAGE(pB[0], &lds[1][1][0][0], 64);
    STAGE(pB[1], &lds[1][1][1][0], 64);
    WAIT_VM8();   // tile 0 landed; tile 1 (8 loads) in flight
    BAR();
    READ_B(pB0k0, pB0k1, b0, 0);     // "prev-P7" slot
    READ_A(pA0k0, pA0k1, a0, 0);     // "prev-P8" slot

    // ---- main loop: iter i computes tiles a=2i (buf0), b=2i+1 (buf1) ----
    for (int i = 0; i < K_DIM / 128; ++i) {
        const int k_a2 = ((2 * i + 2) * 64) & (K_DIM - 1);   // wraps harmlessly last iter
        const int k_b2 = ((2 * i + 3) * 64) & (K_DIM - 1);

        // P1: Q00a | rd a1
        BAR(); WAIT_LGKM0();
        READ_A(pA0k0, pA0k1, a1, 8192);
        SB0();
        __builtin_amdgcn_s_setprio(1);
        QUAD(a0, b0, 0, 0);
        __builtin_amdgcn_s_setprio(0);
        BAR();

        // P2: Q10a | rd b1 | vmcnt(0): publish tile b (8 outstanding, issued prev P7/P8)
        BAR(); WAIT_LGKM0();
        READ_B(pB0k0, pB0k1, b1, 4096);
        SB0();
        __builtin_amdgcn_s_setprio(1);
        QUAD(a1, b0, 1, 0);
        __builtin_amdgcn_s_setprio(0);
        WAIT_VM0();
        BAR();

        // P3: Q01a | st (a+2).A | rd b0' (buf1)
        STAGE(pA[0], &lds[0][0][0][0], k_a2);
        STAGE(pA[1], &lds[0][0][1][0], k_a2);
        BAR(); WAIT_LGKM0();
        READ_B(pB1k0, pB1k1, b0, 0);
        SB0();
        __builtin_amdgcn_s_setprio(1);
        QUAD(a0, b1, 0, 1);
        __builtin_amdgcn_s_setprio(0);
        BAR();

        // P4: Q11a | st (a+2).B | rd a0' (buf1)
        STAGE(pB[0], &lds[0][1][0][0], k_a2);
        STAGE(pB[1], &lds[0][1][1][0], k_a2);
        BAR(); WAIT_LGKM0();
        READ_A(pA1k0, pA1k1, a0, 0);
        SB0();
        __builtin_amdgcn_s_setprio(1);
        QUAD(a1, b1, 1, 1);
        __builtin_amdgcn_s_setprio(0);
        BAR();

        // P5: Q00b | rd a1'
        BAR(); WAIT_LGKM0();
        READ_A(pA1k0, pA1k1, a1, 8192);
        SB0();
        __builtin_amdgcn_s_setprio(1);
        QUAD(a0, b0, 0, 0);
        __builtin_amdgcn_s_setprio(0);
        BAR();

        // P6: Q10b | rd b1' | vmcnt(0): publish tile a+2 (8 outstanding, issued P3/P4)
        BAR(); WAIT_LGKM0();
        READ_B(pB1k0, pB1k1, b1, 4096);
        SB0();
        __builtin_amdgcn_s_setprio(1);
        QUAD(a1, b0, 1, 0);
        __builtin_amdgcn_s_setprio(0);
        WAIT_VM0();
        BAR();

        // P7: Q01b | st (b+2).A | rd b0'' (buf0)
        STAGE(pA[0], &lds[1][0][0][0], k_b2);
        STAGE(pA[1], &lds[1][0][1][0], k_b2);
        BAR(); WAIT_LGKM0();
        READ_B(pB0k0, pB0k1, b0, 0);
        SB0();
        __builtin_amdgcn_s_setprio(1);
        QUAD(a0, b1, 0, 1);
        __builtin_amdgcn_s_setprio(0);
        BAR();

        // P8: Q11b | st (b+2).B | rd a0'' (buf0)
        STAGE(pB[0], &lds[1][1][0][0], k_b2);
        STAGE(pB[1], &lds[1][1][1][0], k_b2);
        BAR(); WAIT_LGKM0();
        READ_A(pA0k0, pA0k1, a0, 0);
        SB0();
        __builtin_amdgcn_s_setprio(1);
        QUAD(a1, b1, 1, 1);
        __builtin_amdgcn_s_setprio(0);
        BAR();
    }

    WAIT_VM0();     // drain wrapped prefetches
    WAIT_LGKM0();   // drain dangling P7/P8 reads before epilogue reuses regs

    // ---- epilogue: C/D layout col=lane&15, row=(lane>>4)*4+j ----
    const int orow = brow + wr * 128 + (lane >> 4) * 4;
    const int ocol = bcol + wc * 64 + (lane & 15);
#pragma unroll
    for (int n = 0; n < 4; ++n) {
        const int c = ocol + n * 16;
        const float bv = bias[c];
#pragma unroll
        for (int m = 0; m < 8; ++m) {
#pragma unroll
            for (int j = 0; j < 4; ++j) {
                C[(size_t)(orow + m * 16 + j) * N_DIM + c] = acc[m][n][j] + bv;
            }
        }
    }
}

// ---------- fallback (ws too small): correct, slow fp32 ----------
__global__ __launch_bounds__(256)
void gemm_f32_naive(const float* __restrict__ x, const float* __restrict__ w,
                    const float* __restrict__ bias, float* __restrict__ out) {
    const size_t total = (size_t)M_DIM * N_DIM;
    const size_t stride = (size_t)gridDim.x * blockDim.x;
    for (size_t idx = (size_t)blockIdx.x * blockDim.x + threadIdx.x; idx < total; idx += stride) {
        const int b = (int)(idx / N_DIM);
        const int o = (int)(idx % N_DIM);
        const float* xr = x + (size_t)b * K_DIM;
        const float* wr = w + (size_t)o * K_DIM;
        float s = bias[o];
        for (int k = 0; k < K_DIM; ++k) s = fmaf(xr[k], wr[k], s);
        out[idx] = s;
    }
}

extern "C" void kernel_launch(void* const* d_in, const int* in_sizes, int n_in,
                              void* d_out, int out_size, void* d_ws, size_t ws_size,
                              hipStream_t stream) {
    const float* x    = (const float*)d_in[0];
    const float* w    = (const float*)d_in[1];
    const float* bias = (const float*)d_in[2];
    float* out = (float*)d_out;

    const size_t xb_elems = (size_t)M_DIM * K_DIM;
    const size_t wb_elems = (size_t)N_DIM * K_DIM;
    const size_t need = (xb_elems + wb_elems) * sizeof(u16);

    if (ws_size >= need) {
        u16* xb = (u16*)d_ws;
        u16* wb = xb + xb_elems;
        cvt_f32_to_bf16_k<<<2048, 256, 0, stream>>>(x, xb, (int)(xb_elems / 8));
        cvt_f32_to_bf16_k<<<2048, 256, 0, stream>>>(w, wb, (int)(wb_elems / 8));
        const int nwg = (M_DIM / 256) * (N_DIM / 256);   // 32*16 = 512
        gemm_8phase<<<nwg, 512, 0, stream>>>(xb, wb, bias, out);
    } else {
        gemm_f32_naive<<<4096, 256, 0, stream>>>(x, w, bias, out);
    }
}

// Round 9
// 272.378 us; speedup vs baseline: 1.0346x; 1.0346x over previous
//
#include <hip/hip_runtime.h>
#include <stdint.h>

typedef unsigned short u16;
typedef __attribute__((ext_vector_type(8))) short short8;
typedef __attribute__((ext_vector_type(4))) float f32x4;

#define M_DIM 8192
#define N_DIM 4096
#define K_DIM 4096

// ---------- fp32 -> bf16 (RNE), 8 elems/thread ----------
__device__ inline u16 f32_to_bf16_rne(float f) {
    uint32_t b = __builtin_bit_cast(uint32_t, f);
    b += 0x7fffu + ((b >> 16) & 1u);
    return (u16)(b >> 16);
}

__global__ __launch_bounds__(256)
void cvt_f32_to_bf16_k(const float* __restrict__ in, u16* __restrict__ out, int n_vec8) {
    int stride = gridDim.x * blockDim.x;
    for (int i = blockIdx.x * blockDim.x + threadIdx.x; i < n_vec8; i += stride) {
        const float4* p = reinterpret_cast<const float4*>(in) + 2 * (size_t)i;
        float4 a = p[0];
        float4 b = p[1];
        float v[8] = {a.x, a.y, a.z, a.w, b.x, b.y, b.z, b.w};
        short8 r;
#pragma unroll
        for (int j = 0; j < 8; ++j) r[j] = (short)f32_to_bf16_rne(v[j]);
        *reinterpret_cast<short8*>(out + 8 * (size_t)i) = r;
    }
}

// ---------- 256x256 8-phase bf16 GEMM (m201 template, in-phase reads) ----------
// A: [M][K] bf16, B: [N][K] bf16 (B^T), C: [M][N] f32
// 512 threads = 8 waves (2M x 4N); per-wave 128x64; BK=64.
// LDS: [dbuf][mat][half][128*64] bf16 = 128 KiB. Swizzle S(a)=a^(((a>>7)&7)<<4),
// folded into precomputed per-lane base pointers.
//
// Quadrant order: Q00(a0,b0) Q01(a0,b1) Q10(a1,b0) Q11(a1,b1).
// Phase = { in-phase ds_reads; 1 half-tile STAGE; [lgkm(8) hint]; BAR;
//           lgkm(0); setprio(1); 16 MFMA; setprio(0); [vmcnt]; BAR }.
// Reads/phase: 12,4,8,0,12,4,8,0. Stages: P1 b.Ah1 | P3 a'.Bh0 | P4 a'.Bh1 |
// P5 a'.Ah0 | P6 a'.Ah1 | P7 b'.Bh0 | P8 b'.Bh1 + b'.Ah0.
// WAR ledger: buf0.B last read P2 < stage P3/P4; buf0.A last read P3 < P5/P6;
// buf1.B last read P6 < P7/P8; buf1.A last read P7 < P8/nextP1. Cross-wave
// safety: wave V's reads of phase p drain at its lgkm0(p) before arriving at
// close-BAR(p); any stage in phase >= p+1 issues after passing that barrier.
// vmcnt: P4-wait outstanding {prevP7:2,prevP8:4,P1:2,P3:2,P4:2}=12 -> vm(4)
// drains the 8 oldest = tile b exactly. P8-wait outstanding {P3..P8}=14 ->
// vm(6) drains P3..P6 = tile a+2 exactly.

#define BAR() do { asm volatile("" ::: "memory"); __builtin_amdgcn_s_barrier(); asm volatile("" ::: "memory"); } while (0)
#define WAIT_LGKM0() do { asm volatile("s_waitcnt lgkmcnt(0)" ::: "memory"); __builtin_amdgcn_sched_barrier(0); } while (0)
#define HINT_LGKM8() asm volatile("s_waitcnt lgkmcnt(8)" ::: "memory")
#define WAIT_VM6() asm volatile("s_waitcnt vmcnt(6)" ::: "memory")
#define WAIT_VM4() asm volatile("s_waitcnt vmcnt(4)" ::: "memory")
#define WAIT_VM0() asm volatile("s_waitcnt vmcnt(0)" ::: "memory")

// 16 MFMA: 4 m-frags x 2 n-frags x 2 k-slices
#define QUAD(AA, BB, MH, NH)                                                      \
    _Pragma("unroll")                                                             \
    for (int ks = 0; ks < 2; ++ks) {                                              \
        _Pragma("unroll")                                                         \
        for (int m = 0; m < 4; ++m) {                                             \
            _Pragma("unroll")                                                     \
            for (int n = 0; n < 2; ++n) {                                         \
                acc[(MH) * 4 + m][(NH) * 2 + n] =                                 \
                    __builtin_amdgcn_mfma_f32_16x16x32_bf16(                      \
                        AA[ks][m], BB[ks][n], acc[(MH) * 4 + m][(NH) * 2 + n],    \
                        0, 0, 0);                                                 \
            }                                                                     \
        }                                                                         \
    }

// A fragment reads: base pointers P0(ks=0)/P1(ks=1), MHOFF in {0, 8192} bytes
#define READ_A(P0, P1, AA, MHOFF)                                                 \
    _Pragma("unroll")                                                             \
    for (int m = 0; m < 4; ++m) {                                                 \
        AA[0][m] = *reinterpret_cast<const short8*>((P0) + (MHOFF) + m * 2048);   \
        AA[1][m] = *reinterpret_cast<const short8*>((P1) + (MHOFF) + m * 2048);   \
    }

// B fragment reads: NHOFF in {0, 4096} bytes
#define READ_B(P0, P1, BB, NHOFF)                                                 \
    _Pragma("unroll")                                                             \
    for (int n = 0; n < 2; ++n) {                                                 \
        BB[0][n] = *reinterpret_cast<const short8*>((P0) + (NHOFF) + n * 2048);   \
        BB[1][n] = *reinterpret_cast<const short8*>((P1) + (NHOFF) + n * 2048);   \
    }

__global__ __launch_bounds__(512, 2)
void gemm_8phase(const u16* __restrict__ A, const u16* __restrict__ B,
                 const float* __restrict__ bias, float* __restrict__ C) {
    __shared__ __align__(16) u16 lds[2][2][2][128 * 64];   // 128 KiB

    const int tid  = threadIdx.x;
    const int wave = tid >> 6;
    const int lane = tid & 63;

    // T1: XCD-aware bijective swizzle (nwg=512, 512%8==0)
    const uint32_t wg = (blockIdx.x & 7u) * 64u + (blockIdx.x >> 3);
    const int bx = (int)(wg % (N_DIM / 256));
    const int by = (int)(wg / (N_DIM / 256));
    const int brow = by * 256;
    const int bcol = bx * 256;

    const int wr = wave >> 2;   // 0..1 -> 128 output rows each
    const int wc = wave & 3;    // 0..3 -> 64 output cols each

    // staging: physical chunk cp (linear gload_lds dest) holds LOGICAL chunk
    // cl = cp ^ ((cp>>3)&7)  (16B-chunk form of S; involution)
    const uint32_t cp0 = (uint32_t)(wave * 64 + lane);
    const uint32_t cp1 = cp0 + 512u;
    const uint32_t cl0 = cp0 ^ ((cp0 >> 3) & 7u);
    const uint32_t cl1 = cp1 ^ ((cp1 >> 3) & 7u);
    const uint32_t sr0 = cl0 >> 3, sc0 = (cl0 & 7u) * 8u;
    const uint32_t sr1 = cl1 >> 3, sc1 = (cl1 & 7u) * 8u;

    const u16* pA[2] = { A + (size_t)(brow)       * K_DIM,
                         A + (size_t)(brow + 128) * K_DIM };
    const u16* pB[2] = { B + (size_t)(bcol)       * K_DIM,
                         B + (size_t)(bcol + 128) * K_DIM };

    // precomputed swizzled per-lane ds_read bases
    const uint32_t kb   = (uint32_t)(lane >> 4) * 16u;
    const uint32_t sw   = (uint32_t)(lane & 7) << 4;
    const uint32_t aoff = (uint32_t)(lane & 15) * 128u + kb;
    const uint32_t boff = (uint32_t)(wc & 1) * 8192u + (uint32_t)(lane & 15) * 128u + kb;

    const char* As0 = (const char*)&lds[0][0][wr][0];
    const char* As1 = (const char*)&lds[1][0][wr][0];
    const char* Bs0 = (const char*)&lds[0][1][wc >> 1][0];
    const char* Bs1 = (const char*)&lds[1][1][wc >> 1][0];

    const char* pA0k0 = As0 + ((aoff)        ^ sw);
    const char* pA0k1 = As0 + ((aoff + 64u)  ^ sw);
    const char* pA1k0 = As1 + ((aoff)        ^ sw);
    const char* pA1k1 = As1 + ((aoff + 64u)  ^ sw);
    const char* pB0k0 = Bs0 + ((boff)        ^ sw);
    const char* pB0k1 = Bs0 + ((boff + 64u)  ^ sw);
    const char* pB1k0 = Bs1 + ((boff)        ^ sw);
    const char* pB1k1 = Bs1 + ((boff + 64u)  ^ sw);

    auto STAGE = [&](const u16* gbase, u16* lhalf, int k0) {
        __builtin_amdgcn_global_load_lds(
            (const __attribute__((address_space(1))) uint32_t*)(gbase + (size_t)sr0 * K_DIM + k0 + sc0),
            (__attribute__((address_space(3))) uint32_t*)(lhalf + wave * 512), 16, 0, 0);
        __builtin_amdgcn_global_load_lds(
            (const __attribute__((address_space(1))) uint32_t*)(gbase + (size_t)sr1 * K_DIM + k0 + sc1),
            (__attribute__((address_space(3))) uint32_t*)(lhalf + 4096 + wave * 512), 16, 0, 0);
    };

    f32x4 acc[8][4];
#pragma unroll
    for (int m = 0; m < 8; ++m)
#pragma unroll
        for (int n = 0; n < 4; ++n) acc[m][n] = (f32x4){0.f, 0.f, 0.f, 0.f};

    short8 a0[2][4], a1[2][4], b0[2][2], b1[2][2];

    // ---- prologue: tile a=0 (8 loads) + tile b=1 {Bh0,Bh1,Ah0} (6 loads) ----
    STAGE(pA[0], &lds[0][0][0][0], 0);    // a.Ah0
    STAGE(pA[1], &lds[0][0][1][0], 0);    // a.Ah1
    STAGE(pB[0], &lds[0][1][0][0], 0);    // a.Bh0
    STAGE(pB[1], &lds[0][1][1][0], 0);    // a.Bh1
    STAGE(pB[0], &lds[1][1][0][0], 64);   // b.Bh0
    STAGE(pB[1], &lds[1][1][1][0], 64);   // b.Bh1
    STAGE(pA[0], &lds[1][0][0][0], 64);   // b.Ah0
    WAIT_VM6();   // tile a landed; b's 6 in flight
    BAR();

    // ---- main loop: iter i computes tiles a=2i (buf0), b=2i+1 (buf1) ----
    for (int i = 0; i < K_DIM / 128; ++i) {
        const int k_b  = (2 * i + 1) * 64;                   // <= 4032, no wrap
        const int k_a2 = ((2 * i + 2) * 64) & (K_DIM - 1);   // wraps harmlessly last iter
        const int k_b2 = ((2 * i + 3) * 64) & (K_DIM - 1);

        // P1: rd a0,b0 (12) | stage b.Ah1 | Q00
        READ_A(pA0k0, pA0k1, a0, 0);
        READ_B(pB0k0, pB0k1, b0, 0);
        STAGE(pA[1], &lds[1][0][1][0], k_b);
        HINT_LGKM8();
        BAR(); WAIT_LGKM0();
        __builtin_amdgcn_s_setprio(1);
        QUAD(a0, b0, 0, 0);
        __builtin_amdgcn_s_setprio(0);
        BAR();

        // P2: rd b1 (4) | Q01
        READ_B(pB0k0, pB0k1, b1, 4096);
        BAR(); WAIT_LGKM0();
        __builtin_amdgcn_s_setprio(1);
        QUAD(a0, b1, 0, 1);
        __builtin_amdgcn_s_setprio(0);
        BAR();

        // P3: rd a1 (8) | stage (a+2).Bh0 | Q10
        READ_A(pA0k0, pA0k1, a1, 8192);
        STAGE(pB[0], &lds[0][1][0][0], k_a2);
        BAR(); WAIT_LGKM0();
        __builtin_amdgcn_s_setprio(1);
        QUAD(a1, b0, 1, 0);
        __builtin_amdgcn_s_setprio(0);
        BAR();

        // P4: stage (a+2).Bh1 | Q11 | vmcnt(4): tile b landed
        STAGE(pB[1], &lds[0][1][1][0], k_a2);
        BAR(); WAIT_LGKM0();
        __builtin_amdgcn_s_setprio(1);
        QUAD(a1, b1, 1, 1);
        __builtin_amdgcn_s_setprio(0);
        WAIT_VM4();
        BAR();

        // P5: rd a0,b0 from buf1 (12) | stage (a+2).Ah0 | Q00
        READ_A(pA1k0, pA1k1, a0, 0);
        READ_B(pB1k0, pB1k1, b0, 0);
        STAGE(pA[0], &lds[0][0][0][0], k_a2);
        HINT_LGKM8();
        BAR(); WAIT_LGKM0();
        __builtin_amdgcn_s_setprio(1);
        QUAD(a0, b0, 0, 0);
        __builtin_amdgcn_s_setprio(0);
        BAR();

        // P6: rd b1 (4) | stage (a+2).Ah1 | Q01
        READ_B(pB1k0, pB1k1, b1, 4096);
        STAGE(pA[1], &lds[0][0][1][0], k_a2);
        BAR(); WAIT_LGKM0();
        __builtin_amdgcn_s_setprio(1);
        QUAD(a0, b1, 0, 1);
        __builtin_amdgcn_s_setprio(0);
        BAR();

        // P7: rd a1 (8) | stage (b+2).Bh0 | Q10
        READ_A(pA1k0, pA1k1, a1, 8192);
        STAGE(pB[0], &lds[1][1][0][0], k_b2);
        BAR(); WAIT_LGKM0();
        __builtin_amdgcn_s_setprio(1);
        QUAD(a1, b0, 1, 0);
        __builtin_amdgcn_s_setprio(0);
        BAR();

        // P8: stage (b+2).Bh1 + (b+2).Ah0 | Q11 | vmcnt(6): tile a+2 landed
        STAGE(pB[1], &lds[1][1][1][0], k_b2);
        STAGE(pA[0], &lds[1][0][0][0], k_b2);
        BAR(); WAIT_LGKM0();
        __builtin_amdgcn_s_setprio(1);
        QUAD(a1, b1, 1, 1);
        __builtin_amdgcn_s_setprio(0);
        WAIT_VM6();
        BAR();
    }

    WAIT_VM0();     // drain wrapped prefetches
    WAIT_LGKM0();   // safety drain before epilogue

    // ---- epilogue: C/D layout col=lane&15, row=(lane>>4)*4+j ----
    const int orow = brow + wr * 128 + (lane >> 4) * 4;
    const int ocol = bcol + wc * 64 + (lane & 15);
#pragma unroll
    for (int n = 0; n < 4; ++n) {
        const int c = ocol + n * 16;
        const float bv = bias[c];
#pragma unroll
        for (int m = 0; m < 8; ++m) {
#pragma unroll
            for (int j = 0; j < 4; ++j) {
                C[(size_t)(orow + m * 16 + j) * N_DIM + c] = acc[m][n][j] + bv;
            }
        }
    }
}

// ---------- fallback (ws too small): correct, slow fp32 ----------
__global__ __launch_bounds__(256)
void gemm_f32_naive(const float* __restrict__ x, const float* __restrict__ w,
                    const float* __restrict__ bias, float* __restrict__ out) {
    const size_t total = (size_t)M_DIM * N_DIM;
    const size_t stride = (size_t)gridDim.x * blockDim.x;
    for (size_t idx = (size_t)blockIdx.x * blockDim.x + threadIdx.x; idx < total; idx += stride) {
        const int b = (int)(idx / N_DIM);
        const int o = (int)(idx % N_DIM);
        const float* xr = x + (size_t)b * K_DIM;
        const float* wr = w + (size_t)o * K_DIM;
        float s = bias[o];
        for (int k = 0; k < K_DIM; ++k) s = fmaf(xr[k], wr[k], s);
        out[idx] = s;
    }
}

extern "C" void kernel_launch(void* const* d_in, const int* in_sizes, int n_in,
                              void* d_out, int out_size, void* d_ws, size_t ws_size,
                              hipStream_t stream) {
    const float* x    = (const float*)d_in[0];
    const float* w    = (const float*)d_in[1];
    const float* bias = (const float*)d_in[2];
    float* out = (float*)d_out;

    const size_t xb_elems = (size_t)M_DIM * K_DIM;
    const size_t wb_elems = (size_t)N_DIM * K_DIM;
    const size_t need = (xb_elems + wb_elems) * sizeof(u16);

    if (ws_size >= need) {
        u16* xb = (u16*)d_ws;
        u16* wb = xb + xb_elems;
        cvt_f32_to_bf16_k<<<2048, 256, 0, stream>>>(x, xb, (int)(xb_elems / 8));
        cvt_f32_to_bf16_k<<<2048, 256, 0, stream>>>(w, wb, (int)(wb_elems / 8));
        const int nwg = (M_DIM / 256) * (N_DIM / 256);   // 32*16 = 512
        gemm_8phase<<<nwg, 512, 0, stream>>>(xb, wb, bias, out);
    } else {
        gemm_f32_naive<<<4096, 256, 0, stream>>>(x, w, bias, out);
    }
}

// Round 10
// 269.968 us; speedup vs baseline: 1.0438x; 1.0089x over previous
//
#include <hip/hip_runtime.h>
#include <stdint.h>

typedef unsigned short u16;
typedef __attribute__((ext_vector_type(8))) short short8;
typedef __attribute__((ext_vector_type(4))) float f32x4;

#define M_DIM 8192
#define N_DIM 4096
#define K_DIM 4096

// ---------- fp32 -> bf16 (RNE), 8 elems/thread ----------
__device__ inline u16 f32_to_bf16_rne(float f) {
    uint32_t b = __builtin_bit_cast(uint32_t, f);
    b += 0x7fffu + ((b >> 16) & 1u);
    return (u16)(b >> 16);
}

__global__ __launch_bounds__(256)
void cvt_f32_to_bf16_k(const float* __restrict__ in, u16* __restrict__ out, int n_vec8) {
    int stride = gridDim.x * blockDim.x;
    for (int i = blockIdx.x * blockDim.x + threadIdx.x; i < n_vec8; i += stride) {
        const float4* p = reinterpret_cast<const float4*>(in) + 2 * (size_t)i;
        float4 a = p[0];
        float4 b = p[1];
        float v[8] = {a.x, a.y, a.z, a.w, b.x, b.y, b.z, b.w};
        short8 r;
#pragma unroll
        for (int j = 0; j < 8; ++j) r[j] = (short)f32_to_bf16_rne(v[j]);
        *reinterpret_cast<short8*>(out + 8 * (size_t)i) = r;
    }
}

// ---------- 256x256 8-phase bf16 GEMM: counted-lgkm JIT pipeline ----------
// A: [M][K] bf16, B: [N][K] bf16 (B^T), C: [M][N] f32
// 512 threads = 8 waves (2M x 4N); per-wave 128x64; BK=64.
// LDS: [dbuf][mat][half][128*64] bf16 = 128 KiB. Swizzle S(a)=a^(((a>>7)&7)<<4)
// folded into precomputed per-lane base pointers (8 of them: buf x mat x ks).
//
// Quad16 = 4m x 4n MFMA at ONE k-slice. Tile order: (mh0,k0)(mh0,k1)(mh1,k0)
// (mh1,k1). Reads are JIT ONE PHASE AHEAD and the post-barrier wait is the
// COUNTED lgkmcnt(N = reads issued this phase): it drains exactly the prior
// phase's reads (this quad's operands) while the just-issued reads drain
// under the MFMA cluster. Reads/phase/wave: 8,4,4,8,8,4,4,8.
//   P1: rd aB<-a.mh0k1, bB<-a.k1 | st b.Ah0      | lgkm(8) | Q(aA,bA,mh0)
//   P2: rd aA<-a.mh1k0           | st b.Ah1      | lgkm(4) | Q(aB,bB,mh0)
//   P3: rd aB<-a.mh1k1           | st (a+2).Bh0  | lgkm(4) | Q(aA,bA,mh1) | vm(2)
//   P4: rd aA<-b.mh0k0, bA<-b.k0 | st (a+2).Bh1  | lgkm(8) | Q(aB,bB,mh1)
//   P5: rd aB<-b.mh0k1, bB<-b.k1 | st (a+2).Ah0  | lgkm(8) | Q(aA,bA,mh0)
//   P6: rd aA<-b.mh1k0           | st (a+2).Ah1  | lgkm(4) | Q(aB,bB,mh0)
//   P7: rd aB<-b.mh1k1           | st (b+2).Bh0  | lgkm(4) | Q(aA,bA,mh1) | vm(2)
//   P8: rd aA<-a'.mh0k0,bA<-a'.k0| st (b+2).Bh1  | lgkm(8) | Q(aB,bB,mh1)
// lgkm ledger: outstanding at wait = prev-phase N + this-phase N; counted wait
// always drains exactly prev. Stage WAR: buf0.B free P2-close (stage P3/P4),
// buf0.A free P4-close (P5/P6), buf1.B free P6-close (P7/P8), buf1.A free
// P8-close (P1/P2). vmcnt(2)@P3: 10 loads out, drains 8 = tile b (prev-P7,P8,
// P1,P2). vmcnt(2)@P7: drains P3..P6 = tile a+2. Reg WAR: every aX/bX
// overwrite is >=1 phase after its last MFMA use (all 8 phases checked).

#define BAR() do { asm volatile("" ::: "memory"); __builtin_amdgcn_s_barrier(); asm volatile("" ::: "memory"); } while (0)
#define LGKM(n) do { asm volatile("s_waitcnt lgkmcnt(" #n ")" ::: "memory"); __builtin_amdgcn_sched_barrier(0); } while (0)
#define WAIT_VM4() asm volatile("s_waitcnt vmcnt(4)" ::: "memory")
#define WAIT_VM2() asm volatile("s_waitcnt vmcnt(2)" ::: "memory")
#define WAIT_VM0() asm volatile("s_waitcnt vmcnt(0)" ::: "memory")

// 16 MFMA: 4 m-frags x 4 n-frags at one k-slice
#define QUAD16(AA, BB, MH)                                                        \
    _Pragma("unroll")                                                             \
    for (int m = 0; m < 4; ++m) {                                                 \
        _Pragma("unroll")                                                         \
        for (int n = 0; n < 4; ++n) {                                             \
            acc[(MH) * 4 + m][n] =                                                \
                __builtin_amdgcn_mfma_f32_16x16x32_bf16(                          \
                    AA[m], BB[n], acc[(MH) * 4 + m][n], 0, 0, 0);                 \
        }                                                                         \
    }

// 4 A-frag reads at one ks: base pointer P (ks folded), MHOFF in {0, 8192}
#define READ_A4(AA, P, MHOFF)                                                     \
    _Pragma("unroll")                                                             \
    for (int m = 0; m < 4; ++m) {                                                 \
        AA[m] = *reinterpret_cast<const short8*>((P) + (MHOFF) + m * 2048);       \
    }

// 4 B-frag reads at one ks (all n): base pointer P (ks + wave-slab folded)
#define READ_B4(BB, P)                                                            \
    _Pragma("unroll")                                                             \
    for (int n = 0; n < 4; ++n) {                                                 \
        BB[n] = *reinterpret_cast<const short8*>((P) + n * 2048);                 \
    }

__global__ __launch_bounds__(512, 2)
void gemm_8phase(const u16* __restrict__ A, const u16* __restrict__ B,
                 const float* __restrict__ bias, float* __restrict__ C) {
    __shared__ __align__(16) u16 lds[2][2][2][128 * 64];   // 128 KiB

    const int tid  = threadIdx.x;
    const int wave = tid >> 6;
    const int lane = tid & 63;

    // T1: XCD-aware bijective swizzle (nwg=512, 512%8==0)
    const uint32_t wg = (blockIdx.x & 7u) * 64u + (blockIdx.x >> 3);
    const int bx = (int)(wg % (N_DIM / 256));
    const int by = (int)(wg / (N_DIM / 256));
    const int brow = by * 256;
    const int bcol = bx * 256;

    const int wr = wave >> 2;   // 0..1 -> 128 output rows each
    const int wc = wave & 3;    // 0..3 -> 64 output cols each

    // staging: physical chunk cp (linear gload_lds dest) holds LOGICAL chunk
    // cl = cp ^ ((cp>>3)&7)  (16B-chunk form of S; involution)
    const uint32_t cp0 = (uint32_t)(wave * 64 + lane);
    const uint32_t cp1 = cp0 + 512u;
    const uint32_t cl0 = cp0 ^ ((cp0 >> 3) & 7u);
    const uint32_t cl1 = cp1 ^ ((cp1 >> 3) & 7u);
    const uint32_t sr0 = cl0 >> 3, sc0 = (cl0 & 7u) * 8u;
    const uint32_t sr1 = cl1 >> 3, sc1 = (cl1 & 7u) * 8u;

    const u16* pA[2] = { A + (size_t)(brow)       * K_DIM,
                         A + (size_t)(brow + 128) * K_DIM };
    const u16* pB[2] = { B + (size_t)(bcol)       * K_DIM,
                         B + (size_t)(bcol + 128) * K_DIM };

    // precomputed swizzled per-lane ds_read bases (ks in {0,64B} folded)
    const uint32_t kb   = (uint32_t)(lane >> 4) * 16u;
    const uint32_t sw   = (uint32_t)(lane & 7) << 4;
    const uint32_t aoff = (uint32_t)(lane & 15) * 128u + kb;
    const uint32_t boff = (uint32_t)(wc & 1) * 8192u + (uint32_t)(lane & 15) * 128u + kb;

    const char* As0 = (const char*)&lds[0][0][wr][0];
    const char* As1 = (const char*)&lds[1][0][wr][0];
    const char* Bs0 = (const char*)&lds[0][1][wc >> 1][0];
    const char* Bs1 = (const char*)&lds[1][1][wc >> 1][0];

    const char* pA0k0 = As0 + ((aoff)        ^ sw);
    const char* pA0k1 = As0 + ((aoff + 64u)  ^ sw);
    const char* pA1k0 = As1 + ((aoff)        ^ sw);
    const char* pA1k1 = As1 + ((aoff + 64u)  ^ sw);
    const char* pB0k0 = Bs0 + ((boff)        ^ sw);
    const char* pB0k1 = Bs0 + ((boff + 64u)  ^ sw);
    const char* pB1k0 = Bs1 + ((boff)        ^ sw);
    const char* pB1k1 = Bs1 + ((boff + 64u)  ^ sw);

    auto STAGE = [&](const u16* gbase, u16* lhalf, int k0) {
        __builtin_amdgcn_global_load_lds(
            (const __attribute__((address_space(1))) uint32_t*)(gbase + (size_t)sr0 * K_DIM + k0 + sc0),
            (__attribute__((address_space(3))) uint32_t*)(lhalf + wave * 512), 16, 0, 0);
        __builtin_amdgcn_global_load_lds(
            (const __attribute__((address_space(1))) uint32_t*)(gbase + (size_t)sr1 * K_DIM + k0 + sc1),
            (__attribute__((address_space(3))) uint32_t*)(lhalf + 4096 + wave * 512), 16, 0, 0);
    };

    f32x4 acc[8][4];
#pragma unroll
    for (int m = 0; m < 8; ++m)
#pragma unroll
        for (int n = 0; n < 4; ++n) acc[m][n] = (f32x4){0.f, 0.f, 0.f, 0.f};

    short8 aA[4], aB[4], bA[4], bB[4];

    // ---- prologue: tile a=0 (8 loads) + b.Bh0/Bh1 (4 loads); vmcnt(4);
    //      pre-read R(P1) = aA<-a.mh0k0, bA<-a.k0 ----
    STAGE(pA[0], &lds[0][0][0][0], 0);    // a.Ah0
    STAGE(pA[1], &lds[0][0][1][0], 0);    // a.Ah1
    STAGE(pB[0], &lds[0][1][0][0], 0);    // a.Bh0
    STAGE(pB[1], &lds[0][1][1][0], 0);    // a.Bh1
    STAGE(pB[0], &lds[1][1][0][0], 64);   // b.Bh0
    STAGE(pB[1], &lds[1][1][1][0], 64);   // b.Bh1
    WAIT_VM4();   // tile a landed; b.Bh (4 loads) in flight
    BAR();
    READ_A4(aA, pA0k0, 0);
    READ_B4(bA, pB0k0);

    // ---- main loop: iter i computes tiles a=2i (buf0), b=2i+1 (buf1) ----
    for (int i = 0; i < K_DIM / 128; ++i) {
        const int k_b  = (2 * i + 1) * 64;                   // <= 4032, no wrap
        const int k_a2 = ((2 * i + 2) * 64) & (K_DIM - 1);   // wraps harmlessly last iter
        const int k_b2 = ((2 * i + 3) * 64) & (K_DIM - 1);

        // P1: rd aB<-a.mh0k1, bB<-a.k1 (8) | st b.Ah0 | Q(aA,bA,mh0)
        READ_A4(aB, pA0k1, 0);
        READ_B4(bB, pB0k1);
        STAGE(pA[0], &lds[1][0][0][0], k_b);
        BAR(); LGKM(8);
        __builtin_amdgcn_s_setprio(1);
        QUAD16(aA, bA, 0);
        __builtin_amdgcn_s_setprio(0);
        BAR();

        // P2: rd aA<-a.mh1k0 (4) | st b.Ah1 | Q(aB,bB,mh0)
        READ_A4(aA, pA0k0, 8192);
        STAGE(pA[1], &lds[1][0][1][0], k_b);
        BAR(); LGKM(4);
        __builtin_amdgcn_s_setprio(1);
        QUAD16(aB, bB, 0);
        __builtin_amdgcn_s_setprio(0);
        BAR();

        // P3: rd aB<-a.mh1k1 (4) | st (a+2).Bh0 | Q(aA,bA,mh1) | vm(2): publish b
        READ_A4(aB, pA0k1, 8192);
        STAGE(pB[0], &lds[0][1][0][0], k_a2);
        BAR(); LGKM(4);
        __builtin_amdgcn_s_setprio(1);
        QUAD16(aA, bA, 1);
        __builtin_amdgcn_s_setprio(0);
        WAIT_VM2();
        BAR();

        // P4: rd aA<-b.mh0k0, bA<-b.k0 (8) | st (a+2).Bh1 | Q(aB,bB,mh1)
        READ_A4(aA, pA1k0, 0);
        READ_B4(bA, pB1k0);
        STAGE(pB[1], &lds[0][1][1][0], k_a2);
        BAR(); LGKM(8);
        __builtin_amdgcn_s_setprio(1);
        QUAD16(aB, bB, 1);
        __builtin_amdgcn_s_setprio(0);
        BAR();

        // P5: rd aB<-b.mh0k1, bB<-b.k1 (8) | st (a+2).Ah0 | Q(aA,bA,mh0)
        READ_A4(aB, pA1k1, 0);
        READ_B4(bB, pB1k1);
        STAGE(pA[0], &lds[0][0][0][0], k_a2);
        BAR(); LGKM(8);
        __builtin_amdgcn_s_setprio(1);
        QUAD16(aA, bA, 0);
        __builtin_amdgcn_s_setprio(0);
        BAR();

        // P6: rd aA<-b.mh1k0 (4) | st (a+2).Ah1 | Q(aB,bB,mh0)
        READ_A4(aA, pA1k0, 8192);
        STAGE(pA[1], &lds[0][0][1][0], k_a2);
        BAR(); LGKM(4);
        __builtin_amdgcn_s_setprio(1);
        QUAD16(aB, bB, 0);
        __builtin_amdgcn_s_setprio(0);
        BAR();

        // P7: rd aB<-b.mh1k1 (4) | st (b+2).Bh0 | Q(aA,bA,mh1) | vm(2): publish a+2
        READ_A4(aB, pA1k1, 8192);
        STAGE(pB[0], &lds[1][1][0][0], k_b2);
        BAR(); LGKM(4);
        __builtin_amdgcn_s_setprio(1);
        QUAD16(aA, bA, 1);
        __builtin_amdgcn_s_setprio(0);
        WAIT_VM2();
        BAR();

        // P8: rd aA<-(a+2).mh0k0, bA<-(a+2).k0 (8) | st (b+2).Bh1 | Q(aB,bB,mh1)
        READ_A4(aA, pA0k0, 0);
        READ_B4(bA, pB0k0);
        STAGE(pB[1], &lds[1][1][1][0], k_b2);
        BAR(); LGKM(8);
        __builtin_amdgcn_s_setprio(1);
        QUAD16(aB, bB, 1);
        __builtin_amdgcn_s_setprio(0);
        BAR();
    }

    WAIT_VM0();    // drain wrapped prefetches
    LGKM(0);       // drain dangling JIT reads before epilogue reuses regs

    // ---- epilogue: C/D layout col=lane&15, row=(lane>>4)*4+j ----
    const int orow = brow + wr * 128 + (lane >> 4) * 4;
    const int ocol = bcol + wc * 64 + (lane & 15);
#pragma unroll
    for (int n = 0; n < 4; ++n) {
        const int c = ocol + n * 16;
        const float bv = bias[c];
#pragma unroll
        for (int m = 0; m < 8; ++m) {
#pragma unroll
            for (int j = 0; j < 4; ++j) {
                C[(size_t)(orow + m * 16 + j) * N_DIM + c] = acc[m][n][j] + bv;
            }
        }
    }
}

// ---------- fallback (ws too small): correct, slow fp32 ----------
__global__ __launch_bounds__(256)
void gemm_f32_naive(const float* __restrict__ x, const float* __restrict__ w,
                    const float* __restrict__ bias, float* __restrict__ out) {
    const size_t total = (size_t)M_DIM * N_DIM;
    const size_t stride = (size_t)gridDim.x * blockDim.x;
    for (size_t idx = (size_t)blockIdx.x * blockDim.x + threadIdx.x; idx < total; idx += stride) {
        const int b = (int)(idx / N_DIM);
        const int o = (int)(idx % N_DIM);
        const float* xr = x + (size_t)b * K_DIM;
        const float* wr = w + (size_t)o * K_DIM;
        float s = bias[o];
        for (int k = 0; k < K_DIM; ++k) s = fmaf(xr[k], wr[k], s);
        out[idx] = s;
    }
}

extern "C" void kernel_launch(void* const* d_in, const int* in_sizes, int n_in,
                              void* d_out, int out_size, void* d_ws, size_t ws_size,
                              hipStream_t stream) {
    const float* x    = (const float*)d_in[0];
    const float* w    = (const float*)d_in[1];
    const float* bias = (const float*)d_in[2];
    float* out = (float*)d_out;

    const size_t xb_elems = (size_t)M_DIM * K_DIM;
    const size_t wb_elems = (size_t)N_DIM * K_DIM;
    const size_t need = (xb_elems + wb_elems) * sizeof(u16);

    if (ws_size >= need) {
        u16* xb = (u16*)d_ws;
        u16* wb = xb + xb_elems;
        cvt_f32_to_bf16_k<<<2048, 256, 0, stream>>>(x, xb, (int)(xb_elems / 8));
        cvt_f32_to_bf16_k<<<2048, 256, 0, stream>>>(w, wb, (int)(wb_elems / 8));
        const int nwg = (M_DIM / 256) * (N_DIM / 256);   // 32*16 = 512
        gemm_8phase<<<nwg, 512, 0, stream>>>(xb, wb, bias, out);
    } else {
        gemm_f32_naive<<<4096, 256, 0, stream>>>(x, w, bias, out);
    }
}